// Round 8
// baseline (278.739 us; speedup 1.0000x reference)
//
#include <hip/hip_runtime.h>
#include <hip/hip_bf16.h>
#include <hip/hip_cooperative_groups.h>

namespace cg = cooperative_groups;

#define HASH_BUCKETS 1024
#define BA 4096
#define BB 8192

typedef __attribute__((ext_vector_type(8))) short bf16x8;
typedef __attribute__((ext_vector_type(4))) float f32x4;

__device__ __forceinline__ short f2bf(float x) {
    union { float f; unsigned int u; } c;
    c.f = x;
    unsigned int lsb = (c.u >> 16) & 1u;
    c.u += 0x7fffu + lsb;  // RNE
    return (short)(c.u >> 16);
}

__device__ __forceinline__ void gl_lds16(const void* g, void* l) {
    __builtin_amdgcn_global_load_lds((const __attribute__((address_space(1))) void*)g,
                                     (__attribute__((address_space(3))) void*)l, 16, 0, 0);
}

// ======== MFMA bf16 GEMM tile: 64x64, BK=64, double-buffered 2-phase pipeline ========
// (verified rounds 5-6, unchanged)
template <int MODE>
__device__ __forceinline__ void gemm_tile(short* __restrict__ As, short* __restrict__ Bs,
                                          const short* __restrict__ A,
                                          const short* __restrict__ Bt,
                                          const short* __restrict__ tab,
                                          const short* __restrict__ bmean,
                                          const int* __restrict__ ha,
                                          const float* __restrict__ bias,
                                          void* __restrict__ Cv,
                                          int bm, int bn, int M, int N, int K) {
    const int tid = threadIdx.x;
    const int l = tid & 63, w = tid >> 6;
    const int wm = w >> 1, wn = w & 1;

    const int r0 = (w * 2 + 0) * 8 + (l >> 3);
    const int r1 = (w * 2 + 1) * 8 + (l >> 3);
    const int sk0 = ((l & 7) ^ (r0 & 7)) * 8;
    const int sk1 = ((l & 7) ^ (r1 & 7)) * 8;
    const int arow0 = bm + r0, arow1 = bm + r1;
    const int brow0 = bn + r0, brow1 = bn + r1;
    int ha0 = 0, ha1 = 0;
    if (MODE == 0) { ha0 = ha[arow0]; ha1 = ha[arow1]; }
    const int dst0 = (w * 2 + 0) * 512;
    const int dst1 = (w * 2 + 1) * 512;

    const int lr = l & 15;
    const int g = l >> 4;
    f32x4 acc[2][2] = {};

    auto STAGE = [&](int nb, int kt) {
        const int k0 = kt * 64;
        const short *as0, *as1;
        if (MODE == 0) {
            if (k0 < 256) {
                as0 = &tab[(size_t)arow0 * 256 + k0 + sk0];
                as1 = &tab[(size_t)arow1 * 256 + k0 + sk1];
            } else {
                as0 = &bmean[(size_t)ha0 * 256 + (k0 - 256) + sk0];
                as1 = &bmean[(size_t)ha1 * 256 + (k0 - 256) + sk1];
            }
        } else {
            as0 = &A[(size_t)arow0 * K + k0 + sk0];
            as1 = &A[(size_t)arow1 * K + k0 + sk1];
        }
        gl_lds16(as0, As + nb * 4096 + dst0);
        gl_lds16(as1, As + nb * 4096 + dst1);
        gl_lds16(&Bt[(size_t)brow0 * K + k0 + sk0], Bs + nb * 4096 + dst0);
        gl_lds16(&Bt[(size_t)brow1 * K + k0 + sk1], Bs + nb * 4096 + dst1);
    };

    auto COMPUTE = [&](int nb) {
        const short* ab = As + nb * 4096;
        const short* bb = Bs + nb * 4096;
        bf16x8 af[2][2], bfr[2][2];
#pragma unroll
        for (int mf = 0; mf < 2; ++mf) {
            const int rr = wm * 32 + mf * 16 + lr;
#pragma unroll
            for (int ks = 0; ks < 2; ++ks)
                af[mf][ks] = *(const bf16x8*)&ab[rr * 64 + (((ks * 4 + g) ^ (lr & 7)) * 8)];
        }
#pragma unroll
        for (int nf = 0; nf < 2; ++nf) {
            const int rr = wn * 32 + nf * 16 + lr;
#pragma unroll
            for (int ks = 0; ks < 2; ++ks)
                bfr[nf][ks] = *(const bf16x8*)&bb[rr * 64 + (((ks * 4 + g) ^ (lr & 7)) * 8)];
        }
#pragma unroll
        for (int ks = 0; ks < 2; ++ks)
#pragma unroll
            for (int mf = 0; mf < 2; ++mf)
#pragma unroll
                for (int nf = 0; nf < 2; ++nf)
                    acc[mf][nf] = __builtin_amdgcn_mfma_f32_16x16x32_bf16(
                        af[mf][ks], bfr[nf][ks], acc[mf][nf], 0, 0, 0);
    };

    const int nt = K >> 6;
    STAGE(0, 0);
    asm volatile("s_waitcnt vmcnt(0)" ::: "memory");
    __syncthreads();
    for (int t = 0; t < nt; ++t) {
        const int cur = t & 1;
        if (t + 1 < nt) STAGE(cur ^ 1, t + 1);
        COMPUTE(cur);
        asm volatile("s_waitcnt vmcnt(0)" ::: "memory");
        __syncthreads();
    }

#pragma unroll
    for (int mf = 0; mf < 2; ++mf)
#pragma unroll
        for (int nf = 0; nf < 2; ++nf) {
            const int col = bn + wn * 32 + nf * 16 + lr;
            const int rbase = bm + wm * 32 + mf * 16 + ((l >> 4) << 2);
            float bv = 0.f;
            if (MODE < 2) bv = bias[col];
#pragma unroll
            for (int i = 0; i < 4; ++i) {
                const float x = acc[mf][nf][i] + bv;
                const int row = rbase + i;
                if (MODE == 0)
                    ((short*)Cv)[(size_t)row * N + col] = f2bf(fmaxf(x, 0.f));
                else if (MODE == 1)
                    ((float*)Cv)[(size_t)row * N + col] = x;
                else
                    ((short*)Cv)[(size_t)col * M + row] = f2bf(x);
            }
        }
}

// ---------- shared prep-job body (used by mega P0b and fallback prep) ----------
__device__ __forceinline__ void prep_job(int b, int t, char* smem,
                                         const float* W1, const float* Wo,
                                         const float* W2, const float* b2,
                                         const float* bo, const float* ta,
                                         const int* ka, short* W1T, short* WoT,
                                         short* W2b, short* tab, int* ha,
                                         float* bfused) {
    if (b < 64) {  // W1T transpose
        float(*tl)[65] = (float(*)[65])smem;
        const int tr = (b >> 3) * 64, tc = (b & 7) * 64;
        const int c = t & 63, r0 = t >> 6;
#pragma unroll
        for (int i = 0; i < 16; ++i) {
            int r = r0 + i * 4;
            tl[r][c] = W1[(size_t)(tr + r) * 512 + tc + c];
        }
        __syncthreads();
#pragma unroll
        for (int i = 0; i < 16; ++i) {
            int r = r0 + i * 4;
            W1T[(size_t)(tc + r) * 512 + tr + c] = f2bf(tl[c][r]);
        }
    } else if (b < 80) {  // WoT transpose
        float(*tl)[65] = (float(*)[65])smem;
        const int bb2 = b - 64;
        const int tr = (bb2 >> 2) * 64, tc = (bb2 & 3) * 64;
        const int c = t & 63, r0 = t >> 6;
#pragma unroll
        for (int i = 0; i < 16; ++i) {
            int r = r0 + i * 4;
            tl[r][c] = Wo[(size_t)(tr + r) * 256 + tc + c];
        }
        __syncthreads();
#pragma unroll
        for (int i = 0; i < 16; ++i) {
            int r = r0 + i * 4;
            WoT[(size_t)(tc + r) * 256 + tr + c] = f2bf(tl[c][r]);
        }
    } else if (b < 88) {  // W2b convert
        const int g = (b - 80) * 256 + t;
#pragma unroll
        for (int i = 0; i < 16; ++i) {
            int e = g + i * 2048;
            float4 v = ((const float4*)W2)[e];
            short4 s;
            s.x = f2bf(v.x); s.y = f2bf(v.y); s.z = f2bf(v.z); s.w = f2bf(v.w);
            ((short4*)W2b)[e] = s;
        }
    } else if (b < 152) {  // tab convert
        const int bb2 = b - 88;
#pragma unroll
        for (int i = 0; i < 16; ++i) {
            int e = bb2 * 4096 + i * 256 + t;
            float4 v = ((const float4*)ta)[e];
            short4 s;
            s.x = f2bf(v.x); s.y = f2bf(v.y); s.z = f2bf(v.z); s.w = f2bf(v.w);
            ((short4*)tab)[e] = s;
        }
    } else if (b < 168) {  // hash_a
        const int r = (b - 152) * 256 + t;
        int4 k4 = ((const int4*)ka)[r];
        ha[r] = (k4.x + k4.y + k4.z + k4.w) & (HASH_BUCKETS - 1);
    } else if (b == 168) {  // bfused
        float acc = bo[t];
        for (int k = 0; k < 256; ++k) acc += b2[k] * Wo[(size_t)k * 256 + t];
        bfused[t] = acc;
    }
}

// ================== cooperative mega-kernel, 512 blocks (2/CU) ==================
// P0: block b computes bucket means 2b and 2b+1 in ONE kb scan; blocks 0..168
//     additionally run one prep job.
// P1: all 512 blocks -> G1 tiles; blocks 480..511 then do the 32 w2woT tiles.
// P2: blocks 0..255 -> G2 tiles.
__global__ __launch_bounds__(256, 2) void mega_kernel(
    const float* __restrict__ ta, const float* __restrict__ tb,
    const int* __restrict__ ka, const int* __restrict__ kb,
    const float* __restrict__ W1, const float* __restrict__ b1,
    const float* __restrict__ W2, const float* __restrict__ b2,
    const float* __restrict__ Wo, const float* __restrict__ bo,
    float* __restrict__ out, int* __restrict__ ha, short* __restrict__ bmean,
    short* __restrict__ tab, short* __restrict__ W1T, short* __restrict__ WoT,
    short* __restrict__ W2b, short* __restrict__ w2woT,
    float* __restrict__ bfused, short* __restrict__ hbuf) {
    __shared__ __align__(16) char smem[32768];
    cg::grid_group grid = cg::this_grid();
    const int b = blockIdx.x;
    const int t = threadIdx.x;

    // ---------------- PHASE 0a: two bucket means per block ----------------
    {
        float* part = (float*)smem;       // [2][4][256] floats = 8 KB
        int* pcnt = (int*)(smem + 8192);  // [2][4]
        const int h0 = 2 * b, h1 = 2 * b + 1;
        const int w = t >> 6, l = t & 63;
        float a0 = 0.f, a1 = 0.f, a2 = 0.f, a3 = 0.f;
        float c0f = 0.f, c1f = 0.f, c2f = 0.f, c3f = 0.f;
        int cnt0 = 0, cnt1 = 0;
        for (int it = 0; it < 32; ++it) {
            const int base = w * 2048 + it * 64;
            int4 k4 = ((const int4*)kb)[base + l];
            const int hh = (k4.x + k4.y + k4.z + k4.w) & 1023;
            unsigned long long m0 = __ballot(hh == h0);
            unsigned long long m1 = __ballot(hh == h1);
            cnt0 += __popcll(m0);
            cnt1 += __popcll(m1);
            while (m0) {
                int j = base + (__ffsll((long long)m0) - 1);
                m0 &= m0 - 1;
                const float* rp = tb + (size_t)j * 256;
                a0 += rp[l]; a1 += rp[l + 64]; a2 += rp[l + 128]; a3 += rp[l + 192];
            }
            while (m1) {
                int j = base + (__ffsll((long long)m1) - 1);
                m1 &= m1 - 1;
                const float* rp = tb + (size_t)j * 256;
                c0f += rp[l]; c1f += rp[l + 64]; c2f += rp[l + 128]; c3f += rp[l + 192];
            }
        }
        part[w * 256 + l] = a0; part[w * 256 + l + 64] = a1;
        part[w * 256 + l + 128] = a2; part[w * 256 + l + 192] = a3;
        part[1024 + w * 256 + l] = c0f; part[1024 + w * 256 + l + 64] = c1f;
        part[1024 + w * 256 + l + 128] = c2f; part[1024 + w * 256 + l + 192] = c3f;
        if (l == 0) { pcnt[w] = cnt0; pcnt[4 + w] = cnt1; }
        __syncthreads();
        float s0 = part[t] + part[256 + t] + part[512 + t] + part[768 + t];
        float s1 = part[1024 + t] + part[1280 + t] + part[1536 + t] + part[1792 + t];
        int n0 = pcnt[0] + pcnt[1] + pcnt[2] + pcnt[3];
        int n1 = pcnt[4] + pcnt[5] + pcnt[6] + pcnt[7];
        bmean[(size_t)h0 * 256 + t] = f2bf(s0 / (float)max(n0, 1));
        bmean[(size_t)h1 * 256 + t] = f2bf(s1 / (float)max(n1, 1));
        __syncthreads();  // smem reuse below
    }
    // ---------------- PHASE 0b: prep jobs on blocks 0..168 ----------------
    prep_job(b, t, smem, W1, Wo, W2, b2, bo, ta, ka, W1T, WoT, W2b, tab, ha, bfused);

    __threadfence();
    grid.sync();

    // ---------------- PHASE 1: G1 tiles (+ w2woT on blocks 480..511) ----------------
    short* As = (short*)smem;
    short* Bs = (short*)(smem + 16384);
    gemm_tile<0>(As, Bs, nullptr, W1T, tab, bmean, ha, b1, hbuf,
                 (b >> 3) * 64, (b & 7) * 64, BA, 512, 512);
    if (b >= 480) {
        const int tt = b - 480;
        __syncthreads();
        gemm_tile<2>(As, Bs, W2b, WoT, nullptr, nullptr, nullptr, nullptr, w2woT,
                     (tt >> 2) * 64, (tt & 3) * 64, 512, 256, 256);
    }

    __threadfence();
    grid.sync();

    // ---------------- PHASE 2: G2 tiles ----------------
    if (b < 256) {
        gemm_tile<1>(As, Bs, hbuf, w2woT, nullptr, nullptr, nullptr, bfused, out,
                     (b >> 2) * 64, (b & 3) * 64, BA, 256, 512);
    }
}

// ================== fallback path (verified round-6 kernels) ==================
__global__ __launch_bounds__(256) void prep_kernel(
    const float* __restrict__ W1, const float* __restrict__ Wo,
    const float* __restrict__ W2, const float* __restrict__ b2,
    const float* __restrict__ bo, const float* __restrict__ ta,
    const float* __restrict__ tb, const int* __restrict__ ka,
    const int* __restrict__ kb, short* __restrict__ W1T,
    short* __restrict__ WoT, short* __restrict__ W2b,
    short* __restrict__ tab, int* __restrict__ ha,
    float* __restrict__ bfused, short* __restrict__ bmean) {
    __shared__ __align__(16) char smem[36896];
    const int blk = blockIdx.x;
    const int t = threadIdx.x;
    if (blk < 169) {
        prep_job(blk, t, smem, W1, Wo, W2, b2, bo, ta, ka, W1T, WoT, W2b, tab, ha, bfused);
    } else {
        int* sh = (int*)smem;
        float* part = (float*)(smem + 32768);
        int* pcnt = (int*)(smem + 36864);
        const int h = blk - 169;
        const int w = t >> 6, l = t & 63;
#pragma unroll 4
        for (int i = 0; i < 32; ++i) {
            int r = i * 256 + t;
            int4 k4 = ((const int4*)kb)[r];
            sh[r] = (k4.x + k4.y + k4.z + k4.w) & (HASH_BUCKETS - 1);
        }
        __syncthreads();
        float a0 = 0.f, a1 = 0.f, a2 = 0.f, a3 = 0.f;
        int cnt = 0;
#pragma unroll 4
        for (int it = 0; it < 32; ++it) {
            int base = w * 2048 + it * 64;
            unsigned long long m = __ballot(sh[base + l] == h);
            cnt += __popcll(m);
            while (m) {
                int j = base + (__ffsll((long long)m) - 1);
                m &= (m - 1);
                const float* row = tb + (size_t)j * 256;
                a0 += row[l]; a1 += row[l + 64]; a2 += row[l + 128]; a3 += row[l + 192];
            }
        }
        part[w * 256 + l] = a0; part[w * 256 + l + 64] = a1;
        part[w * 256 + l + 128] = a2; part[w * 256 + l + 192] = a3;
        if (l == 0) pcnt[w] = cnt;
        __syncthreads();
        float s = part[t] + part[256 + t] + part[512 + t] + part[768 + t];
        int c = pcnt[0] + pcnt[1] + pcnt[2] + pcnt[3];
        bmean[(size_t)h * 256 + t] = f2bf(s / (float)max(c, 1));
    }
}

__global__ __launch_bounds__(256) void g1_kernel(const short* __restrict__ W1T,
                                                 const short* __restrict__ tab,
                                                 const short* __restrict__ bmean,
                                                 const int* __restrict__ ha,
                                                 const float* __restrict__ b1,
                                                 short* __restrict__ hbuf,
                                                 const short* __restrict__ W2b,
                                                 const short* __restrict__ WoT,
                                                 short* __restrict__ w2woT) {
    __shared__ short As[2 * 4096];
    __shared__ short Bs[2 * 4096];
    if (blockIdx.y < 64)
        gemm_tile<0>(As, Bs, nullptr, W1T, tab, bmean, ha, b1, hbuf,
                     blockIdx.y * 64, blockIdx.x * 64, BA, 512, 512);
    else
        gemm_tile<2>(As, Bs, W2b, WoT, nullptr, nullptr, nullptr, nullptr, w2woT,
                     blockIdx.x * 64, (blockIdx.y - 64) * 64, 512, 256, 256);
}

__global__ __launch_bounds__(256) void g2_kernel(const short* __restrict__ hbuf,
                                                 const short* __restrict__ w2woT,
                                                 const float* __restrict__ bfused,
                                                 float* __restrict__ out) {
    __shared__ short As[2 * 4096];
    __shared__ short Bs[2 * 4096];
    gemm_tile<1>(As, Bs, hbuf, w2woT, nullptr, nullptr, nullptr, bfused, out,
                 blockIdx.y * 64, blockIdx.x * 64, BA, 256, 512);
}

extern "C" void kernel_launch(void* const* d_in, const int* in_sizes, int n_in,
                              void* d_out, int out_size, void* d_ws, size_t ws_size,
                              hipStream_t stream) {
    const float* ta = (const float*)d_in[0];
    const float* tb = (const float*)d_in[1];
    const int* ka = (const int*)d_in[2];
    const int* kb = (const int*)d_in[3];
    const float* W1 = (const float*)d_in[4];
    const float* b1 = (const float*)d_in[5];
    const float* W2 = (const float*)d_in[6];
    const float* b2 = (const float*)d_in[7];
    const float* Wo = (const float*)d_in[8];
    const float* bo = (const float*)d_in[9];
    float* out = (float*)d_out;

    char* ws = (char*)d_ws;
    int* ha = (int*)(ws + 0);                // 16 KB
    short* bmean = (short*)(ws + 16384);     // 512 KB bf16 1024x256
    short* tab = (short*)(ws + 540672);      // 2 MB  bf16 4096x256
    short* W1T = (short*)(ws + 2637824);     // 512 KB bf16 512x512
    short* w2woT = (short*)(ws + 3162112);   // 256 KB bf16 256x512
    float* bfused = (float*)(ws + 3424256);  // 1 KB
    short* hbuf = (short*)(ws + 3425280);    // 4 MB  bf16 4096x512
    short* WoT = (short*)(ws + 7619584);     // 128 KB bf16 256x256
    short* W2b = (short*)(ws + 7750656);     // 256 KB bf16 512x256

    int maxb = 0;
    hipError_t oe = hipOccupancyMaxActiveBlocksPerMultiprocessor(&maxb, mega_kernel, 256, 0);
    if (oe == hipSuccess && maxb >= 2) {
        void* args[] = {&ta, &tb, &ka, &kb, &W1, &b1, &W2, &b2, &Wo, &bo,
                        &out, &ha, &bmean, &tab, &W1T, &WoT, &W2b, &w2woT,
                        &bfused, &hbuf};
        hipLaunchCooperativeKernel((const void*)mega_kernel, dim3(512), dim3(256),
                                   args, 0, stream);
    } else {
        prep_kernel<<<1193, 256, 0, stream>>>(W1, Wo, W2, b2, bo, ta, tb, ka, kb,
                                              W1T, WoT, W2b, tab, ha, bfused, bmean);
        g1_kernel<<<dim3(8, 68), 256, 0, stream>>>(W1T, tab, bmean, ha, b1, hbuf,
                                                   W2b, WoT, w2woT);
        g2_kernel<<<dim3(4, 64), 256, 0, stream>>>(hbuf, w2woT, bfused, out);
    }
}

// Round 9
// 40.394 us; speedup vs baseline: 6.9006x; 6.9006x over previous
//
#include <hip/hip_runtime.h>
#include <hip/hip_bf16.h>

#define HASH_BUCKETS 1024
#define BA 4096
#define BB 8192

typedef __attribute__((ext_vector_type(8))) short bf16x8;
typedef __attribute__((ext_vector_type(4))) float f32x4;

__device__ __forceinline__ short f2bf(float x) {
    union { float f; unsigned int u; } c;
    c.f = x;
    unsigned int lsb = (c.u >> 16) & 1u;
    c.u += 0x7fffu + lsb;  // RNE
    return (short)(c.u >> 16);
}

__device__ __forceinline__ void gl_lds16(const void* g, void* l) {
    __builtin_amdgcn_global_load_lds((const __attribute__((address_space(1))) void*)g,
                                     (__attribute__((address_space(3))) void*)l, 16, 0, 0);
}

// ======== MFMA bf16 GEMM tile v3: 64x64, BK=128, double-buffered 2-phase ========
// LDS [row][k16 ^ (row&7)] both-sides swizzle; gl_lds dest linear (wave base +
// lane*16B), per-lane global source pre-swizzled, ds_read applies same XOR.
// MODE 0: A gathered from [tab | bmean[ha]] (K=512), +bias, ReLU, bf16 out [M][N]
// MODE 1: plain bf16 A, +bias, f32 out [M][N]
// MODE 2: plain bf16 A, no bias, bf16 out TRANSPOSED [N][M]
template <int MODE>
__device__ __forceinline__ void gemm_tile(short* __restrict__ As, short* __restrict__ Bs,
                                          const short* __restrict__ A,
                                          const short* __restrict__ Bt,
                                          const short* __restrict__ tab,
                                          const short* __restrict__ bmean,
                                          const int* __restrict__ ha,
                                          const float* __restrict__ bias,
                                          void* __restrict__ Cv,
                                          int bm, int bn, int M, int N, int K) {
    const int tid = threadIdx.x;
    const int l = tid & 63, w = tid >> 6;
    const int wm = w >> 1, wn = w & 1;

    // staging: call c in 0..3 covers rows c*16 + w*4 .. +3; lane l -> row
    // c*16 + w*4 + (l>>4), 16B-unit (l&15) pre-XORed by row&7 on the SOURCE.
    const int sr = w * 4 + (l >> 4);           // row within 16-row call group
    const int sk = ((l & 15) ^ (sr & 7)) * 8;  // swizzled k offset (shorts)
    int harr[4];
    if (MODE == 0) {
#pragma unroll
        for (int c = 0; c < 4; ++c) harr[c] = ha[bm + c * 16 + sr];
    }
    const int lr = l & 15;
    const int g = l >> 4;
    f32x4 acc[2][2] = {};

    auto STAGE = [&](int nb, int kt) {
        const int k0 = kt * 128;
#pragma unroll
        for (int c = 0; c < 4; ++c) {
            const int r = c * 16 + sr;
            const short* asrc;
            if (MODE == 0) {
                asrc = (k0 < 256) ? &tab[(size_t)(bm + r) * 256 + k0 + sk]
                                  : &bmean[(size_t)harr[c] * 256 + (k0 - 256) + sk];
            } else {
                asrc = &A[(size_t)(bm + r) * K + k0 + sk];
            }
            // dest: wave-uniform base; HW adds lane*16B -> rows c*16+w*4..+3 linear
            gl_lds16(asrc, As + nb * 8192 + (c * 16 + w * 4) * 128);
            gl_lds16(&Bt[(size_t)(bn + r) * K + k0 + sk],
                     Bs + nb * 8192 + (c * 16 + w * 4) * 128);
        }
    };

    auto COMPUTE = [&](int nb) {
        const short* ab = As + nb * 8192;
        const short* bb = Bs + nb * 8192;
        bf16x8 af[2][4], bfr[2][4];
#pragma unroll
        for (int mf = 0; mf < 2; ++mf) {
            const int rr = wm * 32 + mf * 16 + lr;
#pragma unroll
            for (int ks = 0; ks < 4; ++ks)
                af[mf][ks] = *(const bf16x8*)&ab[rr * 128 + (((ks * 4 + g) ^ (rr & 7)) * 8)];
        }
#pragma unroll
        for (int nf = 0; nf < 2; ++nf) {
            const int rr = wn * 32 + nf * 16 + lr;
#pragma unroll
            for (int ks = 0; ks < 4; ++ks)
                bfr[nf][ks] = *(const bf16x8*)&bb[rr * 128 + (((ks * 4 + g) ^ (rr & 7)) * 8)];
        }
#pragma unroll
        for (int ks = 0; ks < 4; ++ks)
#pragma unroll
            for (int mf = 0; mf < 2; ++mf)
#pragma unroll
                for (int nf = 0; nf < 2; ++nf)
                    acc[mf][nf] = __builtin_amdgcn_mfma_f32_16x16x32_bf16(
                        af[mf][ks], bfr[nf][ks], acc[mf][nf], 0, 0, 0);
    };

    const int nt = K >> 7;  // BK=128
    STAGE(0, 0);
    asm volatile("s_waitcnt vmcnt(0)" ::: "memory");
    __syncthreads();
    for (int t = 0; t < nt; ++t) {
        const int cur = t & 1;
        if (t + 1 < nt) STAGE(cur ^ 1, t + 1);
        COMPUTE(cur);
        asm volatile("s_waitcnt vmcnt(0)" ::: "memory");
        __syncthreads();
    }

    // epilogue (verified mapping): D elem i -> row (l>>4)*4+i, col lr
#pragma unroll
    for (int mf = 0; mf < 2; ++mf)
#pragma unroll
        for (int nf = 0; nf < 2; ++nf) {
            const int col = bn + wn * 32 + nf * 16 + lr;
            const int rbase = bm + wm * 32 + mf * 16 + ((l >> 4) << 2);
            float bv = 0.f;
            if (MODE < 2) bv = bias[col];
#pragma unroll
            for (int i = 0; i < 4; ++i) {
                const float x = acc[mf][nf][i] + bv;
                const int row = rbase + i;
                if (MODE == 0)
                    ((short*)Cv)[(size_t)row * N + col] = f2bf(fmaxf(x, 0.f));
                else if (MODE == 1)
                    ((float*)Cv)[(size_t)row * N + col] = x;
                else
                    ((short*)Cv)[(size_t)col * M + row] = f2bf(x);
            }
        }
}

// ---------------- prep jobs (verified rounds 6-8) ----------------
__device__ __forceinline__ void prep_job(int b, int t, char* smem,
                                         const float* W1, const float* Wo,
                                         const float* W2, const float* b2,
                                         const float* bo, const float* ta,
                                         const int* ka, short* W1T, short* WoT,
                                         short* W2b, short* tab, int* ha,
                                         float* bfused) {
    if (b < 64) {  // W1T transpose
        float(*tl)[65] = (float(*)[65])smem;
        const int tr = (b >> 3) * 64, tc = (b & 7) * 64;
        const int c = t & 63, r0 = t >> 6;
#pragma unroll
        for (int i = 0; i < 16; ++i) {
            int r = r0 + i * 4;
            tl[r][c] = W1[(size_t)(tr + r) * 512 + tc + c];
        }
        __syncthreads();
#pragma unroll
        for (int i = 0; i < 16; ++i) {
            int r = r0 + i * 4;
            W1T[(size_t)(tc + r) * 512 + tr + c] = f2bf(tl[c][r]);
        }
    } else if (b < 80) {  // WoT transpose
        float(*tl)[65] = (float(*)[65])smem;
        const int bb2 = b - 64;
        const int tr = (bb2 >> 2) * 64, tc = (bb2 & 3) * 64;
        const int c = t & 63, r0 = t >> 6;
#pragma unroll
        for (int i = 0; i < 16; ++i) {
            int r = r0 + i * 4;
            tl[r][c] = Wo[(size_t)(tr + r) * 256 + tc + c];
        }
        __syncthreads();
#pragma unroll
        for (int i = 0; i < 16; ++i) {
            int r = r0 + i * 4;
            WoT[(size_t)(tc + r) * 256 + tr + c] = f2bf(tl[c][r]);
        }
    } else if (b < 88) {  // W2b convert
        const int g = (b - 80) * 256 + t;
#pragma unroll
        for (int i = 0; i < 16; ++i) {
            int e = g + i * 2048;
            float4 v = ((const float4*)W2)[e];
            short4 s;
            s.x = f2bf(v.x); s.y = f2bf(v.y); s.z = f2bf(v.z); s.w = f2bf(v.w);
            ((short4*)W2b)[e] = s;
        }
    } else if (b < 152) {  // tab convert
        const int bb2 = b - 88;
#pragma unroll
        for (int i = 0; i < 16; ++i) {
            int e = bb2 * 4096 + i * 256 + t;
            float4 v = ((const float4*)ta)[e];
            short4 s;
            s.x = f2bf(v.x); s.y = f2bf(v.y); s.z = f2bf(v.z); s.w = f2bf(v.w);
            ((short4*)tab)[e] = s;
        }
    } else if (b < 168) {  // hash_a
        const int r = (b - 152) * 256 + t;
        int4 k4 = ((const int4*)ka)[r];
        ha[r] = (k4.x + k4.y + k4.z + k4.w) & (HASH_BUCKETS - 1);
    } else if (b == 168) {  // bfused
        float acc = bo[t];
        for (int k = 0; k < 256; ++k) acc += b2[k] * Wo[(size_t)k * 256 + t];
        bfused[t] = acc;
    }
}

// ---- prep kernel: 512 blocks; block b = bucket means {2b, 2b+1} (one inline kb
// ---- scan, verified R8) + prep job for b < 169.
__global__ __launch_bounds__(256) void prep_kernel(
    const float* __restrict__ W1, const float* __restrict__ Wo,
    const float* __restrict__ W2, const float* __restrict__ b2,
    const float* __restrict__ bo, const float* __restrict__ ta,
    const float* __restrict__ tb, const int* __restrict__ ka,
    const int* __restrict__ kb, short* __restrict__ W1T,
    short* __restrict__ WoT, short* __restrict__ W2b,
    short* __restrict__ tab, int* __restrict__ ha,
    float* __restrict__ bfused, short* __restrict__ bmean) {
    __shared__ __align__(16) char smem[16704];
    const int b = blockIdx.x;
    const int t = threadIdx.x;
    {
        float* part = (float*)smem;       // [2][4][256] floats = 8 KB
        int* pcnt = (int*)(smem + 8192);  // [2][4]
        const int h0 = 2 * b, h1 = 2 * b + 1;
        const int w = t >> 6, l = t & 63;
        float a0 = 0.f, a1 = 0.f, a2 = 0.f, a3 = 0.f;
        float c0f = 0.f, c1f = 0.f, c2f = 0.f, c3f = 0.f;
        int cnt0 = 0, cnt1 = 0;
        for (int it = 0; it < 32; ++it) {
            const int base = w * 2048 + it * 64;
            int4 k4 = ((const int4*)kb)[base + l];
            const int hh = (k4.x + k4.y + k4.z + k4.w) & 1023;
            unsigned long long m0 = __ballot(hh == h0);
            unsigned long long m1 = __ballot(hh == h1);
            cnt0 += __popcll(m0);
            cnt1 += __popcll(m1);
            while (m0) {
                int j = base + (__ffsll((long long)m0) - 1);
                m0 &= m0 - 1;
                const float* rp = tb + (size_t)j * 256;
                a0 += rp[l]; a1 += rp[l + 64]; a2 += rp[l + 128]; a3 += rp[l + 192];
            }
            while (m1) {
                int j = base + (__ffsll((long long)m1) - 1);
                m1 &= m1 - 1;
                const float* rp = tb + (size_t)j * 256;
                c0f += rp[l]; c1f += rp[l + 64]; c2f += rp[l + 128]; c3f += rp[l + 192];
            }
        }
        part[w * 256 + l] = a0; part[w * 256 + l + 64] = a1;
        part[w * 256 + l + 128] = a2; part[w * 256 + l + 192] = a3;
        part[1024 + w * 256 + l] = c0f; part[1024 + w * 256 + l + 64] = c1f;
        part[1024 + w * 256 + l + 128] = c2f; part[1024 + w * 256 + l + 192] = c3f;
        if (l == 0) { pcnt[w] = cnt0; pcnt[4 + w] = cnt1; }
        __syncthreads();
        float s0 = part[t] + part[256 + t] + part[512 + t] + part[768 + t];
        float s1 = part[1024 + t] + part[1280 + t] + part[1536 + t] + part[1792 + t];
        int n0 = pcnt[0] + pcnt[1] + pcnt[2] + pcnt[3];
        int n1 = pcnt[4] + pcnt[5] + pcnt[6] + pcnt[7];
        bmean[(size_t)h0 * 256 + t] = f2bf(s0 / (float)max(n0, 1));
        bmean[(size_t)h1 * 256 + t] = f2bf(s1 / (float)max(n1, 1));
        __syncthreads();  // smem reuse below
    }
    prep_job(b, t, smem, W1, Wo, W2, b2, bo, ta, ka, W1T, WoT, W2b, tab, ha, bfused);
}

// G1 launch: y<64 -> G1 tiles (4096x512x512); y>=64 -> w2woT tiles (512x256x256)
__global__ __launch_bounds__(256) void g1_kernel(const short* __restrict__ W1T,
                                                 const short* __restrict__ tab,
                                                 const short* __restrict__ bmean,
                                                 const int* __restrict__ ha,
                                                 const float* __restrict__ b1,
                                                 short* __restrict__ hbuf,
                                                 const short* __restrict__ W2b,
                                                 const short* __restrict__ WoT,
                                                 short* __restrict__ w2woT) {
    __shared__ short As[2 * 8192];
    __shared__ short Bs[2 * 8192];
    if (blockIdx.y < 64)
        gemm_tile<0>(As, Bs, nullptr, W1T, tab, bmean, ha, b1, hbuf,
                     blockIdx.y * 64, blockIdx.x * 64, BA, 512, 512);
    else
        gemm_tile<2>(As, Bs, W2b, WoT, nullptr, nullptr, nullptr, nullptr, w2woT,
                     blockIdx.x * 64, (blockIdx.y - 64) * 64, 512, 256, 256);
}

__global__ __launch_bounds__(256) void g2_kernel(const short* __restrict__ hbuf,
                                                 const short* __restrict__ w2woT,
                                                 const float* __restrict__ bfused,
                                                 float* __restrict__ out) {
    __shared__ short As[2 * 8192];
    __shared__ short Bs[2 * 8192];
    gemm_tile<1>(As, Bs, hbuf, w2woT, nullptr, nullptr, nullptr, bfused, out,
                 blockIdx.y * 64, blockIdx.x * 64, BA, 256, 512);
}

extern "C" void kernel_launch(void* const* d_in, const int* in_sizes, int n_in,
                              void* d_out, int out_size, void* d_ws, size_t ws_size,
                              hipStream_t stream) {
    const float* ta = (const float*)d_in[0];
    const float* tb = (const float*)d_in[1];
    const int* ka = (const int*)d_in[2];
    const int* kb = (const int*)d_in[3];
    const float* W1 = (const float*)d_in[4];
    const float* b1 = (const float*)d_in[5];
    const float* W2 = (const float*)d_in[6];
    const float* b2 = (const float*)d_in[7];
    const float* Wo = (const float*)d_in[8];
    const float* bo = (const float*)d_in[9];
    float* out = (float*)d_out;

    char* ws = (char*)d_ws;
    int* ha = (int*)(ws + 0);                // 16 KB
    short* bmean = (short*)(ws + 16384);     // 512 KB bf16 1024x256
    short* tab = (short*)(ws + 540672);      // 2 MB  bf16 4096x256
    short* W1T = (short*)(ws + 2637824);     // 512 KB bf16 512x512
    short* w2woT = (short*)(ws + 3162112);   // 256 KB bf16 256x512
    float* bfused = (float*)(ws + 3424256);  // 1 KB
    short* hbuf = (short*)(ws + 3425280);    // 4 MB  bf16 4096x512
    short* WoT = (short*)(ws + 7619584);     // 128 KB bf16 256x256
    short* W2b = (short*)(ws + 7750656);     // 256 KB bf16 512x256

    // 1. prep: bucket means (2/block, inline kb hash) + W1T/WoT/W2b/tab/ha/bfused
    prep_kernel<<<512, 256, 0, stream>>>(W1, Wo, W2, b2, bo, ta, tb, ka, kb,
                                         W1T, WoT, W2b, tab, ha, bfused, bmean);
    // 2. G1 (+ w2woT tiles): hbuf = relu([tab | bmean[ha]] @ W1 + b1)
    g1_kernel<<<dim3(8, 68), 256, 0, stream>>>(W1T, tab, bmean, ha, b1, hbuf,
                                               W2b, WoT, w2woT);
    // 3. G2: out = hbuf @ w2wo + bfused
    g2_kernel<<<dim3(4, 64), 256, 0, stream>>>(hbuf, w2woT, bfused, out);
}

// Round 10
// 36.420 us; speedup vs baseline: 7.6534x; 1.1091x over previous
//
#include <hip/hip_runtime.h>
#include <hip/hip_bf16.h>

#define HASH_BUCKETS 1024
#define BA 4096
#define BB 8192

typedef __attribute__((ext_vector_type(8))) short bf16x8;
typedef __attribute__((ext_vector_type(4))) float f32x4;

__device__ __forceinline__ short f2bf(float x) {
    union { float f; unsigned int u; } c;
    c.f = x;
    unsigned int lsb = (c.u >> 16) & 1u;
    c.u += 0x7fffu + lsb;  // RNE
    return (short)(c.u >> 16);
}

__device__ __forceinline__ void gl_lds16(const void* g, void* l) {
    __builtin_amdgcn_global_load_lds((const __attribute__((address_space(1))) void*)g,
                                     (__attribute__((address_space(3))) void*)l, 16, 0, 0);
}

// ======== MFMA bf16 GEMM tile: 64x64, BK=64, double-buffered 2-phase pipeline ========
// (verified rounds 5-6 — best measured config; BK=128 variant regressed, see R9)
template <int MODE>
__device__ __forceinline__ void gemm_tile(short* __restrict__ As, short* __restrict__ Bs,
                                          const short* __restrict__ A,
                                          const short* __restrict__ Bt,
                                          const short* __restrict__ tab,
                                          const short* __restrict__ bmean,
                                          const int* __restrict__ ha,
                                          const float* __restrict__ bias,
                                          void* __restrict__ Cv,
                                          int bm, int bn, int M, int N, int K) {
    const int tid = threadIdx.x;
    const int l = tid & 63, w = tid >> 6;
    const int wm = w >> 1, wn = w & 1;

    const int r0 = (w * 2 + 0) * 8 + (l >> 3);
    const int r1 = (w * 2 + 1) * 8 + (l >> 3);
    const int sk0 = ((l & 7) ^ (r0 & 7)) * 8;
    const int sk1 = ((l & 7) ^ (r1 & 7)) * 8;
    const int arow0 = bm + r0, arow1 = bm + r1;
    const int brow0 = bn + r0, brow1 = bn + r1;
    int ha0 = 0, ha1 = 0;
    if (MODE == 0) { ha0 = ha[arow0]; ha1 = ha[arow1]; }
    const int dst0 = (w * 2 + 0) * 512;
    const int dst1 = (w * 2 + 1) * 512;

    const int lr = l & 15;
    const int g = l >> 4;
    f32x4 acc[2][2] = {};

    auto STAGE = [&](int nb, int kt) {
        const int k0 = kt * 64;
        const short *as0, *as1;
        if (MODE == 0) {
            if (k0 < 256) {
                as0 = &tab[(size_t)arow0 * 256 + k0 + sk0];
                as1 = &tab[(size_t)arow1 * 256 + k0 + sk1];
            } else {
                as0 = &bmean[(size_t)ha0 * 256 + (k0 - 256) + sk0];
                as1 = &bmean[(size_t)ha1 * 256 + (k0 - 256) + sk1];
            }
        } else {
            as0 = &A[(size_t)arow0 * K + k0 + sk0];
            as1 = &A[(size_t)arow1 * K + k0 + sk1];
        }
        gl_lds16(as0, As + nb * 4096 + dst0);
        gl_lds16(as1, As + nb * 4096 + dst1);
        gl_lds16(&Bt[(size_t)brow0 * K + k0 + sk0], Bs + nb * 4096 + dst0);
        gl_lds16(&Bt[(size_t)brow1 * K + k0 + sk1], Bs + nb * 4096 + dst1);
    };

    auto COMPUTE = [&](int nb) {
        const short* ab = As + nb * 4096;
        const short* bb = Bs + nb * 4096;
        bf16x8 af[2][2], bfr[2][2];
#pragma unroll
        for (int mf = 0; mf < 2; ++mf) {
            const int rr = wm * 32 + mf * 16 + lr;
#pragma unroll
            for (int ks = 0; ks < 2; ++ks)
                af[mf][ks] = *(const bf16x8*)&ab[rr * 64 + (((ks * 4 + g) ^ (lr & 7)) * 8)];
        }
#pragma unroll
        for (int nf = 0; nf < 2; ++nf) {
            const int rr = wn * 32 + nf * 16 + lr;
#pragma unroll
            for (int ks = 0; ks < 2; ++ks)
                bfr[nf][ks] = *(const bf16x8*)&bb[rr * 64 + (((ks * 4 + g) ^ (lr & 7)) * 8)];
        }
#pragma unroll
        for (int ks = 0; ks < 2; ++ks)
#pragma unroll
            for (int mf = 0; mf < 2; ++mf)
#pragma unroll
                for (int nf = 0; nf < 2; ++nf)
                    acc[mf][nf] = __builtin_amdgcn_mfma_f32_16x16x32_bf16(
                        af[mf][ks], bfr[nf][ks], acc[mf][nf], 0, 0, 0);
    };

    const int nt = K >> 6;
    STAGE(0, 0);
    asm volatile("s_waitcnt vmcnt(0)" ::: "memory");
    __syncthreads();
    for (int t = 0; t < nt; ++t) {
        const int cur = t & 1;
        if (t + 1 < nt) STAGE(cur ^ 1, t + 1);
        COMPUTE(cur);
        asm volatile("s_waitcnt vmcnt(0)" ::: "memory");
        __syncthreads();
    }

    // epilogue (verified mapping): D elem i -> row (l>>4)*4+i, col lr
#pragma unroll
    for (int mf = 0; mf < 2; ++mf)
#pragma unroll
        for (int nf = 0; nf < 2; ++nf) {
            const int col = bn + wn * 32 + nf * 16 + lr;
            const int rbase = bm + wm * 32 + mf * 16 + ((l >> 4) << 2);
            float bv = 0.f;
            if (MODE < 2) bv = bias[col];
#pragma unroll
            for (int i = 0; i < 4; ++i) {
                const float x = acc[mf][nf][i] + bv;
                const int row = rbase + i;
                if (MODE == 0)
                    ((short*)Cv)[(size_t)row * N + col] = f2bf(fmaxf(x, 0.f));
                else if (MODE == 1)
                    ((float*)Cv)[(size_t)row * N + col] = x;
                else
                    ((short*)Cv)[(size_t)col * M + row] = f2bf(x);
            }
        }
}

// ---------------- prep jobs (verified rounds 6-9) ----------------
__device__ __forceinline__ void prep_job(int b, int t, char* smem,
                                         const float* W1, const float* Wo,
                                         const float* W2, const float* b2,
                                         const float* bo, const float* ta,
                                         const int* ka, short* W1T, short* WoT,
                                         short* W2b, short* tab, int* ha,
                                         float* bfused) {
    if (b < 64) {  // W1T transpose
        float(*tl)[65] = (float(*)[65])smem;
        const int tr = (b >> 3) * 64, tc = (b & 7) * 64;
        const int c = t & 63, r0 = t >> 6;
#pragma unroll
        for (int i = 0; i < 16; ++i) {
            int r = r0 + i * 4;
            tl[r][c] = W1[(size_t)(tr + r) * 512 + tc + c];
        }
        __syncthreads();
#pragma unroll
        for (int i = 0; i < 16; ++i) {
            int r = r0 + i * 4;
            W1T[(size_t)(tc + r) * 512 + tr + c] = f2bf(tl[c][r]);
        }
    } else if (b < 80) {  // WoT transpose
        float(*tl)[65] = (float(*)[65])smem;
        const int bb2 = b - 64;
        const int tr = (bb2 >> 2) * 64, tc = (bb2 & 3) * 64;
        const int c = t & 63, r0 = t >> 6;
#pragma unroll
        for (int i = 0; i < 16; ++i) {
            int r = r0 + i * 4;
            tl[r][c] = Wo[(size_t)(tr + r) * 256 + tc + c];
        }
        __syncthreads();
#pragma unroll
        for (int i = 0; i < 16; ++i) {
            int r = r0 + i * 4;
            WoT[(size_t)(tc + r) * 256 + tr + c] = f2bf(tl[c][r]);
        }
    } else if (b < 88) {  // W2b convert
        const int g = (b - 80) * 256 + t;
#pragma unroll
        for (int i = 0; i < 16; ++i) {
            int e = g + i * 2048;
            float4 v = ((const float4*)W2)[e];
            short4 s;
            s.x = f2bf(v.x); s.y = f2bf(v.y); s.z = f2bf(v.z); s.w = f2bf(v.w);
            ((short4*)W2b)[e] = s;
        }
    } else if (b < 152) {  // tab convert
        const int bb2 = b - 88;
#pragma unroll
        for (int i = 0; i < 16; ++i) {
            int e = bb2 * 4096 + i * 256 + t;
            float4 v = ((const float4*)ta)[e];
            short4 s;
            s.x = f2bf(v.x); s.y = f2bf(v.y); s.z = f2bf(v.z); s.w = f2bf(v.w);
            ((short4*)tab)[e] = s;
        }
    } else if (b < 168) {  // hash_a
        const int r = (b - 152) * 256 + t;
        int4 k4 = ((const int4*)ka)[r];
        ha[r] = (k4.x + k4.y + k4.z + k4.w) & (HASH_BUCKETS - 1);
    } else if (b == 168) {  // bfused
        float acc = bo[t];
        for (int k = 0; k < 256; ++k) acc += b2[k] * Wo[(size_t)k * 256 + t];
        bfused[t] = acc;
    }
}

// ---- prep kernel: 681 blocks, UNSTACKED ----
// blocks 0..168  : one prep job each
// blocks 169..680: bucket means {2b, 2b+1}, b = blk-169 (inline kb hash, verified R8/R9)
__global__ __launch_bounds__(256) void prep_kernel(
    const float* __restrict__ W1, const float* __restrict__ Wo,
    const float* __restrict__ W2, const float* __restrict__ b2,
    const float* __restrict__ bo, const float* __restrict__ ta,
    const float* __restrict__ tb, const int* __restrict__ ka,
    const int* __restrict__ kb, short* __restrict__ W1T,
    short* __restrict__ WoT, short* __restrict__ W2b,
    short* __restrict__ tab, int* __restrict__ ha,
    float* __restrict__ bfused, short* __restrict__ bmean) {
    __shared__ __align__(16) char smem[16704];
    const int blk = blockIdx.x;
    const int t = threadIdx.x;
    if (blk < 169) {
        prep_job(blk, t, smem, W1, Wo, W2, b2, bo, ta, ka, W1T, WoT, W2b, tab, ha, bfused);
        return;
    }
    const int b = blk - 169;
    float* part = (float*)smem;       // [2][4][256] floats = 8 KB
    int* pcnt = (int*)(smem + 8192);  // [2][4]
    const int h0 = 2 * b, h1 = 2 * b + 1;
    const int w = t >> 6, l = t & 63;
    float a0 = 0.f, a1 = 0.f, a2 = 0.f, a3 = 0.f;
    float c0f = 0.f, c1f = 0.f, c2f = 0.f, c3f = 0.f;
    int cnt0 = 0, cnt1 = 0;
    for (int it = 0; it < 32; ++it) {
        const int base = w * 2048 + it * 64;
        int4 k4 = ((const int4*)kb)[base + l];
        const int hh = (k4.x + k4.y + k4.z + k4.w) & 1023;
        unsigned long long m0 = __ballot(hh == h0);
        unsigned long long m1 = __ballot(hh == h1);
        cnt0 += __popcll(m0);
        cnt1 += __popcll(m1);
        while (m0) {
            int j = base + (__ffsll((long long)m0) - 1);
            m0 &= m0 - 1;
            const float* rp = tb + (size_t)j * 256;
            a0 += rp[l]; a1 += rp[l + 64]; a2 += rp[l + 128]; a3 += rp[l + 192];
        }
        while (m1) {
            int j = base + (__ffsll((long long)m1) - 1);
            m1 &= m1 - 1;
            const float* rp = tb + (size_t)j * 256;
            c0f += rp[l]; c1f += rp[l + 64]; c2f += rp[l + 128]; c3f += rp[l + 192];
        }
    }
    part[w * 256 + l] = a0; part[w * 256 + l + 64] = a1;
    part[w * 256 + l + 128] = a2; part[w * 256 + l + 192] = a3;
    part[1024 + w * 256 + l] = c0f; part[1024 + w * 256 + l + 64] = c1f;
    part[1024 + w * 256 + l + 128] = c2f; part[1024 + w * 256 + l + 192] = c3f;
    if (l == 0) { pcnt[w] = cnt0; pcnt[4 + w] = cnt1; }
    __syncthreads();
    float s0 = part[t] + part[256 + t] + part[512 + t] + part[768 + t];
    float s1 = part[1024 + t] + part[1280 + t] + part[1536 + t] + part[1792 + t];
    int n0 = pcnt[0] + pcnt[1] + pcnt[2] + pcnt[3];
    int n1 = pcnt[4] + pcnt[5] + pcnt[6] + pcnt[7];
    bmean[(size_t)h0 * 256 + t] = f2bf(s0 / (float)max(n0, 1));
    bmean[(size_t)h1 * 256 + t] = f2bf(s1 / (float)max(n1, 1));
}

// G1 launch: y<64 -> G1 tiles (4096x512x512); y>=64 -> w2woT tiles (512x256x256)
__global__ __launch_bounds__(256) void g1_kernel(const short* __restrict__ W1T,
                                                 const short* __restrict__ tab,
                                                 const short* __restrict__ bmean,
                                                 const int* __restrict__ ha,
                                                 const float* __restrict__ b1,
                                                 short* __restrict__ hbuf,
                                                 const short* __restrict__ W2b,
                                                 const short* __restrict__ WoT,
                                                 short* __restrict__ w2woT) {
    __shared__ short As[2 * 4096];
    __shared__ short Bs[2 * 4096];
    if (blockIdx.y < 64)
        gemm_tile<0>(As, Bs, nullptr, W1T, tab, bmean, ha, b1, hbuf,
                     blockIdx.y * 64, blockIdx.x * 64, BA, 512, 512);
    else
        gemm_tile<2>(As, Bs, W2b, WoT, nullptr, nullptr, nullptr, nullptr, w2woT,
                     blockIdx.x * 64, (blockIdx.y - 64) * 64, 512, 256, 256);
}

__global__ __launch_bounds__(256) void g2_kernel(const short* __restrict__ hbuf,
                                                 const short* __restrict__ w2woT,
                                                 const float* __restrict__ bfused,
                                                 float* __restrict__ out) {
    __shared__ short As[2 * 4096];
    __shared__ short Bs[2 * 4096];
    gemm_tile<1>(As, Bs, hbuf, w2woT, nullptr, nullptr, nullptr, bfused, out,
                 blockIdx.y * 64, blockIdx.x * 64, BA, 256, 512);
}

extern "C" void kernel_launch(void* const* d_in, const int* in_sizes, int n_in,
                              void* d_out, int out_size, void* d_ws, size_t ws_size,
                              hipStream_t stream) {
    const float* ta = (const float*)d_in[0];
    const float* tb = (const float*)d_in[1];
    const int* ka = (const int*)d_in[2];
    const int* kb = (const int*)d_in[3];
    const float* W1 = (const float*)d_in[4];
    const float* b1 = (const float*)d_in[5];
    const float* W2 = (const float*)d_in[6];
    const float* b2 = (const float*)d_in[7];
    const float* Wo = (const float*)d_in[8];
    const float* bo = (const float*)d_in[9];
    float* out = (float*)d_out;

    char* ws = (char*)d_ws;
    int* ha = (int*)(ws + 0);                // 16 KB
    short* bmean = (short*)(ws + 16384);     // 512 KB bf16 1024x256
    short* tab = (short*)(ws + 540672);      // 2 MB  bf16 4096x256
    short* W1T = (short*)(ws + 2637824);     // 512 KB bf16 512x512
    short* w2woT = (short*)(ws + 3162112);   // 256 KB bf16 256x512
    float* bfused = (float*)(ws + 3424256);  // 1 KB
    short* hbuf = (short*)(ws + 3425280);    // 4 MB  bf16 4096x512
    short* WoT = (short*)(ws + 7619584);     // 128 KB bf16 256x256
    short* W2b = (short*)(ws + 7750656);     // 256 KB bf16 512x256

    // 1. prep: prep jobs (blocks 0..168) + bucket-pair means (blocks 169..680)
    prep_kernel<<<681, 256, 0, stream>>>(W1, Wo, W2, b2, bo, ta, tb, ka, kb,
                                         W1T, WoT, W2b, tab, ha, bfused, bmean);
    // 2. G1 (+ w2woT tiles): hbuf = relu([tab | bmean[ha]] @ W1 + b1)
    g1_kernel<<<dim3(8, 68), 256, 0, stream>>>(W1T, tab, bmean, ha, b1, hbuf,
                                               W2b, WoT, w2woT);
    // 3. G2: out = hbuf @ w2wo + bfused
    g2_kernel<<<dim3(4, 64), 256, 0, stream>>>(hbuf, w2woT, bfused, out);
}

// Round 12
// 34.671 us; speedup vs baseline: 8.0396x; 1.0505x over previous
//
#include <hip/hip_runtime.h>
#include <hip/hip_bf16.h>

#define HASH_BUCKETS 1024
#define BA 4096
#define BB 8192

typedef __attribute__((ext_vector_type(8))) short bf16x8;
typedef __attribute__((ext_vector_type(4))) float f32x4;

__device__ __forceinline__ short f2bf(float x) {
    union { float f; unsigned int u; } c;
    c.f = x;
    unsigned int lsb = (c.u >> 16) & 1u;
    c.u += 0x7fffu + lsb;  // RNE
    return (short)(c.u >> 16);
}

__device__ __forceinline__ void gl_lds16(const void* g, void* l) {
    __builtin_amdgcn_global_load_lds((const __attribute__((address_space(1))) void*)g,
                                     (__attribute__((address_space(3))) void*)l, 16, 0, 0);
}

// ================= mega prep kernel (verified R4-R6 best) =================
// blocks 0..63    : W1 (512x512 f32) -> W1T bf16 [n][k]
// blocks 64..79   : Wo (256x256 f32) -> WoT bf16 [n][c] (transpose)
// blocks 80..87   : W2 (512x256 f32) -> W2b bf16 copy
// blocks 88..151  : ta f32 -> tab bf16
// blocks 152..167 : hash_a
// block  168      : bfused = b2 @ Wo + bo (f32)
// blocks 169..1192: bucket means (1 block per bucket; self-computes hash_b)
__global__ __launch_bounds__(256) void prep_kernel(
    const float* __restrict__ W1, const float* __restrict__ Wo,
    const float* __restrict__ W2, const float* __restrict__ b2,
    const float* __restrict__ bo, const float* __restrict__ ta,
    const float* __restrict__ tb, const int* __restrict__ ka,
    const int* __restrict__ kb, short* __restrict__ W1T,
    short* __restrict__ WoT, short* __restrict__ W2b,
    short* __restrict__ tab, int* __restrict__ ha,
    float* __restrict__ bfused, short* __restrict__ bmean) {
    __shared__ __align__(16) char smem[36896];
    const int blk = blockIdx.x;
    const int t = threadIdx.x;
    if (blk < 64) {  // ---- W1T transpose ----
        float(*tl)[65] = (float(*)[65])smem;
        const int tr = (blk >> 3) * 64, tc = (blk & 7) * 64;
        const int c = t & 63, r0 = t >> 6;
#pragma unroll
        for (int i = 0; i < 16; ++i) {
            int r = r0 + i * 4;
            tl[r][c] = W1[(size_t)(tr + r) * 512 + tc + c];
        }
        __syncthreads();
#pragma unroll
        for (int i = 0; i < 16; ++i) {
            int r = r0 + i * 4;
            W1T[(size_t)(tc + r) * 512 + tr + c] = f2bf(tl[c][r]);
        }
    } else if (blk < 80) {  // ---- WoT transpose (256x256) ----
        float(*tl)[65] = (float(*)[65])smem;
        const int b = blk - 64;
        const int tr = (b >> 2) * 64, tc = (b & 3) * 64;
        const int c = t & 63, r0 = t >> 6;
#pragma unroll
        for (int i = 0; i < 16; ++i) {
            int r = r0 + i * 4;
            tl[r][c] = Wo[(size_t)(tr + r) * 256 + tc + c];
        }
        __syncthreads();
#pragma unroll
        for (int i = 0; i < 16; ++i) {
            int r = r0 + i * 4;
            WoT[(size_t)(tc + r) * 256 + tr + c] = f2bf(tl[c][r]);
        }
    } else if (blk < 88) {  // ---- W2b convert ----
        const int g = (blk - 80) * 256 + t;
#pragma unroll
        for (int i = 0; i < 16; ++i) {
            int e = g + i * 2048;
            float4 v = ((const float4*)W2)[e];
            short4 s;
            s.x = f2bf(v.x); s.y = f2bf(v.y); s.z = f2bf(v.z); s.w = f2bf(v.w);
            ((short4*)W2b)[e] = s;
        }
    } else if (blk < 152) {  // ---- tab convert ----
        const int b = blk - 88;
#pragma unroll
        for (int i = 0; i < 16; ++i) {
            int e = b * 4096 + i * 256 + t;
            float4 v = ((const float4*)ta)[e];
            short4 s;
            s.x = f2bf(v.x); s.y = f2bf(v.y); s.z = f2bf(v.z); s.w = f2bf(v.w);
            ((short4*)tab)[e] = s;
        }
    } else if (blk < 168) {  // ---- hash_a ----
        const int r = (blk - 152) * 256 + t;
        int4 k4 = ((const int4*)ka)[r];
        ha[r] = (k4.x + k4.y + k4.z + k4.w) & (HASH_BUCKETS - 1);
    } else if (blk == 168) {  // ---- bfused ----
        float acc = bo[t];
        for (int k = 0; k < 256; ++k) acc += b2[k] * Wo[(size_t)k * 256 + t];
        bfused[t] = acc;
    } else {  // ---- bucket mean: bucket h = blk-169 ----
        int* sh = (int*)smem;                  // 8192 ints
        float* part = (float*)(smem + 32768);  // 4*256 floats
        int* pcnt = (int*)(smem + 36864);      // 4 ints
        const int h = blk - 169;
        const int w = t >> 6, l = t & 63;
#pragma unroll 4
        for (int i = 0; i < 32; ++i) {
            int r = i * 256 + t;
            int4 k4 = ((const int4*)kb)[r];
            sh[r] = (k4.x + k4.y + k4.z + k4.w) & (HASH_BUCKETS - 1);
        }
        __syncthreads();
        float a0 = 0.f, a1 = 0.f, a2 = 0.f, a3 = 0.f;
        int cnt = 0;
#pragma unroll 4
        for (int it = 0; it < 32; ++it) {
            int base = w * 2048 + it * 64;
            unsigned long long m = __ballot(sh[base + l] == h);
            cnt += __popcll(m);
            while (m) {
                int j = base + (__ffsll((long long)m) - 1);
                m &= (m - 1);
                const float* row = tb + (size_t)j * 256;
                a0 += row[l];
                a1 += row[l + 64];
                a2 += row[l + 128];
                a3 += row[l + 192];
            }
        }
        part[w * 256 + l] = a0;
        part[w * 256 + l + 64] = a1;
        part[w * 256 + l + 128] = a2;
        part[w * 256 + l + 192] = a3;
        if (l == 0) pcnt[w] = cnt;
        __syncthreads();
        float s = part[t] + part[256 + t] + part[512 + t] + part[768 + t];
        int c = pcnt[0] + pcnt[1] + pcnt[2] + pcnt[3];
        bmean[(size_t)h * 256 + t] = f2bf(s / (float)max(c, 1));
    }
}

// ======== MFMA bf16 GEMM tile: 64x64, BK=64, double-buffered 2-phase pipeline ========
// LDS: [row][k16^(row&7)] both-sides XOR swizzle (gl_lds dest linear, source k
// pre-swizzled, ds_read applies same XOR) -> conflict-free b128 reads.
// MODE 0: A gathered from [tab | bmean[ha]] (K=512), +bias, ReLU, bf16 out [M][N]
// MODE 1: plain bf16 A, +bias, f32 out [M][N]
// MODE 2: plain bf16 A, no bias, bf16 out TRANSPOSED [N][M]
template <int MODE>
__device__ __forceinline__ void gemm_tile(short* __restrict__ As, short* __restrict__ Bs,
                                          const short* __restrict__ A,
                                          const short* __restrict__ Bt,
                                          const short* __restrict__ tab,
                                          const short* __restrict__ bmean,
                                          const int* __restrict__ ha,
                                          const float* __restrict__ bias,
                                          void* __restrict__ Cv,
                                          int bm, int bn, int M, int N, int K) {
    const int tid = threadIdx.x;
    const int l = tid & 63, w = tid >> 6;
    const int wm = w >> 1, wn = w & 1;

    const int r0 = (w * 2 + 0) * 8 + (l >> 3);
    const int r1 = (w * 2 + 1) * 8 + (l >> 3);
    const int sk0 = ((l & 7) ^ (r0 & 7)) * 8;
    const int sk1 = ((l & 7) ^ (r1 & 7)) * 8;
    const int arow0 = bm + r0, arow1 = bm + r1;
    const int brow0 = bn + r0, brow1 = bn + r1;
    int ha0 = 0, ha1 = 0;
    if (MODE == 0) { ha0 = ha[arow0]; ha1 = ha[arow1]; }
    const int dst0 = (w * 2 + 0) * 512;
    const int dst1 = (w * 2 + 1) * 512;

    const int lr = l & 15;
    const int g = l >> 4;
    f32x4 acc[2][2] = {};

    auto STAGE = [&](int nb, int kt) {
        const int k0 = kt * 64;
        const short *as0, *as1;
        if (MODE == 0) {
            if (k0 < 256) {
                as0 = &tab[(size_t)arow0 * 256 + k0 + sk0];
                as1 = &tab[(size_t)arow1 * 256 + k0 + sk1];
            } else {
                as0 = &bmean[(size_t)ha0 * 256 + (k0 - 256) + sk0];
                as1 = &bmean[(size_t)ha1 * 256 + (k0 - 256) + sk1];
            }
        } else {
            as0 = &A[(size_t)arow0 * K + k0 + sk0];
            as1 = &A[(size_t)arow1 * K + k0 + sk1];
        }
        gl_lds16(as0, As + nb * 4096 + dst0);
        gl_lds16(as1, As + nb * 4096 + dst1);
        gl_lds16(&Bt[(size_t)brow0 * K + k0 + sk0], Bs + nb * 4096 + dst0);
        gl_lds16(&Bt[(size_t)brow1 * K + k0 + sk1], Bs + nb * 4096 + dst1);
    };

    auto COMPUTE = [&](int nb) {
        const short* ab = As + nb * 4096;
        const short* bb = Bs + nb * 4096;
        bf16x8 af[2][2], bfr[2][2];
#pragma unroll
        for (int mf = 0; mf < 2; ++mf) {
            const int rr = wm * 32 + mf * 16 + lr;
#pragma unroll
            for (int ks = 0; ks < 2; ++ks)
                af[mf][ks] = *(const bf16x8*)&ab[rr * 64 + (((ks * 4 + g) ^ (lr & 7)) * 8)];
        }
#pragma unroll
        for (int nf = 0; nf < 2; ++nf) {
            const int rr = wn * 32 + nf * 16 + lr;
#pragma unroll
            for (int ks = 0; ks < 2; ++ks)
                bfr[nf][ks] = *(const bf16x8*)&bb[rr * 64 + (((ks * 4 + g) ^ (lr & 7)) * 8)];
        }
#pragma unroll
        for (int ks = 0; ks < 2; ++ks)
#pragma unroll
            for (int mf = 0; mf < 2; ++mf)
#pragma unroll
                for (int nf = 0; nf < 2; ++nf)
                    acc[mf][nf] = __builtin_amdgcn_mfma_f32_16x16x32_bf16(
                        af[mf][ks], bfr[nf][ks], acc[mf][nf], 0, 0, 0);
    };

    const int nt = K >> 6;
    STAGE(0, 0);
    asm volatile("s_waitcnt vmcnt(0)" ::: "memory");
    __syncthreads();
    for (int t = 0; t < nt; ++t) {
        const int cur = t & 1;
        if (t + 1 < nt) STAGE(cur ^ 1, t + 1);
        COMPUTE(cur);
        asm volatile("s_waitcnt vmcnt(0)" ::: "memory");
        __syncthreads();
    }

    // epilogue (verified mapping): D elem i -> row (l>>4)*4+i, col lr
#pragma unroll
    for (int mf = 0; mf < 2; ++mf)
#pragma unroll
        for (int nf = 0; nf < 2; ++nf) {
            const int col = bn + wn * 32 + nf * 16 + lr;
            const int rbase = bm + wm * 32 + mf * 16 + ((l >> 4) << 2);
            float bv = 0.f;
            if (MODE < 2) bv = bias[col];
#pragma unroll
            for (int i = 0; i < 4; ++i) {
                const float x = acc[mf][nf][i] + bv;
                const int row = rbase + i;
                if (MODE == 0)
                    ((short*)Cv)[(size_t)row * N + col] = f2bf(fmaxf(x, 0.f));
                else if (MODE == 1)
                    ((float*)Cv)[(size_t)row * N + col] = x;
                else
                    ((short*)Cv)[(size_t)col * M + row] = f2bf(x);
            }
        }
}

// G1 launch: y<64 -> G1 tiles (4096x512x512); y>=64 -> w2woT tiles (512x256x256)
__global__ __launch_bounds__(256) void g1_kernel(const short* __restrict__ W1T,
                                                 const short* __restrict__ tab,
                                                 const short* __restrict__ bmean,
                                                 const int* __restrict__ ha,
                                                 const float* __restrict__ b1,
                                                 short* __restrict__ hbuf,
                                                 const short* __restrict__ W2b,
                                                 const short* __restrict__ WoT,
                                                 short* __restrict__ w2woT) {
    __shared__ short As[2 * 4096];
    __shared__ short Bs[2 * 4096];
    if (blockIdx.y < 64)
        gemm_tile<0>(As, Bs, nullptr, W1T, tab, bmean, ha, b1, hbuf,
                     blockIdx.y * 64, blockIdx.x * 64, BA, 512, 512);
    else
        gemm_tile<2>(As, Bs, W2b, WoT, nullptr, nullptr, nullptr, nullptr, w2woT,
                     blockIdx.x * 64, (blockIdx.y - 64) * 64, 512, 256, 256);
}

__global__ __launch_bounds__(256) void g2_kernel(const short* __restrict__ hbuf,
                                                 const short* __restrict__ w2woT,
                                                 const float* __restrict__ bfused,
                                                 float* __restrict__ out) {
    __shared__ short As[2 * 4096];
    __shared__ short Bs[2 * 4096];
    gemm_tile<1>(As, Bs, hbuf, w2woT, nullptr, nullptr, nullptr, bfused, out,
                 blockIdx.y * 64, blockIdx.x * 64, BA, 256, 512);
}

extern "C" void kernel_launch(void* const* d_in, const int* in_sizes, int n_in,
                              void* d_out, int out_size, void* d_ws, size_t ws_size,
                              hipStream_t stream) {
    const float* ta = (const float*)d_in[0];
    const float* tb = (const float*)d_in[1];
    const int* ka = (const int*)d_in[2];
    const int* kb = (const int*)d_in[3];
    const float* W1 = (const float*)d_in[4];
    const float* b1 = (const float*)d_in[5];
    const float* W2 = (const float*)d_in[6];
    const float* b2 = (const float*)d_in[7];
    const float* Wo = (const float*)d_in[8];
    const float* bo = (const float*)d_in[9];
    float* out = (float*)d_out;

    char* ws = (char*)d_ws;
    int* ha = (int*)(ws + 0);                // 16 KB
    short* bmean = (short*)(ws + 16384);     // 512 KB bf16 1024x256
    short* tab = (short*)(ws + 540672);      // 2 MB  bf16 4096x256
    short* W1T = (short*)(ws + 2637824);     // 512 KB bf16 512x512
    short* w2woT = (short*)(ws + 3162112);   // 256 KB bf16 256x512
    float* bfused = (float*)(ws + 3424256);  // 1 KB
    short* hbuf = (short*)(ws + 3425280);    // 4 MB  bf16 4096x512
    short* WoT = (short*)(ws + 7619584);     // 128 KB bf16 256x256
    short* W2b = (short*)(ws + 7750656);     // 256 KB bf16 512x256

    // 1. prep: W1T, WoT, W2b, tab, ha, bfused, bucket means
    prep_kernel<<<1193, 256, 0, stream>>>(W1, Wo, W2, b2, bo, ta, tb, ka, kb,
                                          W1T, WoT, W2b, tab, ha, bfused, bmean);
    // 2. G1 (+ w2woT MFMA tiles): hbuf = relu([tab | bmean[ha]] @ W1 + b1)
    g1_kernel<<<dim3(8, 68), 256, 0, stream>>>(W1T, tab, bmean, ha, b1, hbuf,
                                               W2b, WoT, w2woT);
    // 3. G2: out = hbuf @ w2wo + bfused
    g2_kernel<<<dim3(4, 64), 256, 0, stream>>>(hbuf, w2woT, bfused, out);
}